// Round 8
// baseline (303.825 us; speedup 1.0000x reference)
//
#include <hip/hip_runtime.h>
#include <hip/hip_bf16.h>

#define N_NODES 50000
#define N_EDGES 500000
#define E_AUG   (N_EDGES + N_NODES)   // 550000 (divisible by 16)
#define NH1 4
#define HID 64
#define C2  64

typedef unsigned int uint32;
typedef unsigned short ushort16;
typedef __attribute__((ext_vector_type(8))) short short8v;
typedef __attribute__((ext_vector_type(4))) float f32x4;

__device__ __forceinline__ ushort16 f2bf(float f) {
    union { float f; uint32 u; } v; v.f = f;
    uint32 u = v.u + (0x7FFFu + ((v.u >> 16) & 1u));   // RNE
    return (ushort16)(u >> 16);
}
__device__ __forceinline__ float bf2f(ushort16 h) {
    union { uint32 u; float f; } v; v.u = ((uint32)h) << 16;
    return v.f;
}

// ---------------- fused pack + degree histogram ----------------
// blocks [0,128): weight packing; blocks [128,...): int histogram (4 edges/thread)
// Wbt[k][hc] fp32, k=0..7: rows {Wl0,Wl1,Wr0,Wr1,We0,We1, b1l+b1r, 0} (B operand, alpha MFMA)
// wpk4[k] = {W1l[0][k], W1l[1][k], b1l[k]+bias1[k], 0}  (h-build coeffs)
// Wt[c][k] bf16, c<64 -> W2l[k][c], else W2r[k][c-64]   (B operand, l1out MFMA)

#define PACK_BLOCKS 128
#define HIST_BLOCKS ((N_EDGES / 4 + 255) / 256)   // 489

__global__ void deg_pack_kernel(const int* __restrict__ ei,
                                const float* __restrict__ W1l, const float* __restrict__ b1l,
                                const float* __restrict__ W1r, const float* __restrict__ b1r,
                                const float* __restrict__ W1e, const float* __restrict__ att1,
                                const float* __restrict__ bias1,
                                const float* __restrict__ W2l, const float* __restrict__ W2r,
                                float* __restrict__ Wbt,
                                float4* __restrict__ wpk4, ushort16* __restrict__ Wt,
                                int* __restrict__ deg) {
    const int tid = threadIdx.x;
    if (blockIdx.x < PACK_BLOCKS) {
        int t = blockIdx.x * 256 + tid;
        if (blockIdx.x == 0 && tid < 256) {
            int hc = tid;
            Wbt[0 * 256 + hc] = W1l[hc];
            Wbt[1 * 256 + hc] = W1l[256 + hc];
            Wbt[2 * 256 + hc] = W1r[hc];
            Wbt[3 * 256 + hc] = W1r[256 + hc];
            Wbt[4 * 256 + hc] = W1e[hc];
            Wbt[5 * 256 + hc] = W1e[256 + hc];
            Wbt[6 * 256 + hc] = b1l[hc] + b1r[hc];
            Wbt[7 * 256 + hc] = 0.0f;
            wpk4[hc] = make_float4(W1l[hc], W1l[256 + hc], b1l[hc] + bias1[hc], 0.0f);
        }
        if (t < 128 * 256) {
            int c = t & 127, k = t >> 7;
            float w = (c < 64) ? W2l[k * 64 + c] : W2r[k * 64 + (c - 64)];
            Wt[c * 256 + k] = f2bf(w);
        }
    } else {
        const int e0 = ((blockIdx.x - PACK_BLOCKS) * 256 + tid) * 4;
        if (e0 < N_EDGES) {   // N_EDGES % 4 == 0
            const int4 d4 = *(const int4*)&ei[N_EDGES + e0];
            atomicAdd(&deg[d4.x], 1);
            atomicAdd(&deg[d4.y], 1);
            atomicAdd(&deg[d4.z], 1);
            atomicAdd(&deg[d4.w], 1);
        }
    }
}

// ---------------- CSR scans ----------------

__global__ void scan1_kernel(const int* __restrict__ deg, int* __restrict__ offs,
                             int* __restrict__ bsum) {
    __shared__ int s[256];
    int tid = threadIdx.x;
    int i = blockIdx.x * 256 + tid;
    int v = (i < N_NODES) ? (deg[i] + 1) : 0;   // +1 reserved self-loop slot
    s[tid] = v;
    __syncthreads();
    for (int off = 1; off < 256; off <<= 1) {
        int t = (tid >= off) ? s[tid - off] : 0;
        __syncthreads();
        s[tid] += t;
        __syncthreads();
    }
    if (i < N_NODES) offs[i + 1] = s[tid];
    if (tid == 255) bsum[blockIdx.x] = s[255];
}

__global__ void scan23_kernel(int* __restrict__ offs, const int* __restrict__ bsum, int nb) {
    __shared__ int s[256];
    int tid = threadIdx.x;
    int b = blockIdx.x;
    s[tid] = (tid < nb && tid < b) ? bsum[tid] : 0;
    __syncthreads();
    for (int off = 128; off; off >>= 1) {
        if (tid < off) s[tid] += s[tid + off];
        __syncthreads();
    }
    int base = s[0];
    int i = b * 256 + tid;
    if (i < N_NODES) offs[i + 1] += base;
    if (i == 0) offs[0] = 0;
}

// ---------------- scatter (real edges; slot offs[d] reserved for self-loop) ----

__global__ void scatter_kernel(const int* __restrict__ ei, const float* __restrict__ ea,
                               const int* __restrict__ offs, int* __restrict__ cnt,
                               int* __restrict__ e_src, int* __restrict__ e_dst,
                               float* __restrict__ e_ea) {
    int e = blockIdx.x * 256 + threadIdx.x;
    if (e >= N_EDGES) return;
    int s = ei[e], d = ei[N_EDGES + e];
    float a0 = ea[2 * e + 0], a1 = ea[2 * e + 1];
    int pos = offs[d] + 1 + atomicAdd(&cnt[d], 1);
    e_src[pos] = s;
    e_dst[pos] = d;
    e_ea[2 * pos + 0] = a0;
    e_ea[2 * pos + 1] = a1;
}

// ---------------- self-loop fill: mean edge_attr over node's real edges ----------

__global__ void loop_fill_kernel(const int* __restrict__ offs,
                                 int* __restrict__ e_src, int* __restrict__ e_dst,
                                 float* __restrict__ e_ea) {
    int n = blockIdx.x * 256 + threadIdx.x;
    if (n >= N_NODES) return;
    int beg = offs[n], end = offs[n + 1];
    float s0 = 0.0f, s1 = 0.0f;
    for (int e = beg + 1; e < end; ++e) {
        s0 += e_ea[2 * e + 0];
        s1 += e_ea[2 * e + 1];
    }
    float inv = 1.0f / (float)max(end - beg - 1, 1);
    e_src[beg] = n;
    e_dst[beg] = n;
    e_ea[2 * beg + 0] = s0 * inv;
    e_ea[2 * beg + 1] = s1 * inv;
}

// ---------------- Layer 1 alpha via MFMA ----------------
// Per wave-iter: 16 edges. A[m=edge][k] = u = [xs.x,xs.y,xd.x,xd.y,ae.x,ae.y,1,0...] bf16
// (lanes 0..15 hold their own edge's u as the A fragment; lanes 16..63 all-zero k rows).
// B[k][n] = Wbt[k][tile*16+n]. 16 MFMA -> z[16 edges][256 ch].
// P[edge r][head h] += att*(0.6 z + 0.4|z|); reduce-scatter butterfly over 16 lanes
// lands p for (r,h) on lane r*4+h of each 16-lane group. alpha1 SoA planes per head.

__global__ __launch_bounds__(256) void l1_alpha_kernel(
    const float* __restrict__ x, const int* __restrict__ e_src,
    const int* __restrict__ e_dst, const float* __restrict__ e_ea,
    const float* __restrict__ Wbt, const float* __restrict__ att1,
    float* __restrict__ alpha1) {
    const int tid = threadIdx.x;
    const int lane = tid & 63, w = tid >> 6;
    const int lo = lane & 15;

    // B fragments (16 channel-tiles); zero for lanes >= 16 (k rows 8..31)
    short8v bfrag[16];
    #pragma unroll
    for (int t = 0; t < 16; ++t) {
        short8v b = {0, 0, 0, 0, 0, 0, 0, 0};
        if (lane < 16) {
            #pragma unroll
            for (int i = 0; i < 7; ++i)
                b[i] = (short)f2bf(Wbt[i * 256 + t * 16 + lo]);
        }
        bfrag[t] = b;
    }
    // att coefficients for my channel column (col = lo in each tile)
    float a6[16], a4[16];
    #pragma unroll
    for (int t = 0; t < 16; ++t) {
        float av = att1[t * 16 + lo];
        a6[t] = 0.6f * av;
        a4[t] = 0.4f * av;
    }

    const int nwaves = gridDim.x * 4;
    const int gw = blockIdx.x * 4 + w;
    for (int grp = gw; grp < E_AUG / 16; grp += nwaves) {
        const int e0 = grp * 16;

        short8v afrag = {0, 0, 0, 0, 0, 0, 0, 0};
        if (lane < 16) {
            const int e = e0 + lo;
            const int s = e_src[e], d = e_dst[e];
            const float2 xs = *(const float2*)&x[2 * s];
            const float2 xd = *(const float2*)&x[2 * d];
            const float2 ae = *(const float2*)&e_ea[2 * e];
            afrag[0] = (short)f2bf(xs.x); afrag[1] = (short)f2bf(xs.y);
            afrag[2] = (short)f2bf(xd.x); afrag[3] = (short)f2bf(xd.y);
            afrag[4] = (short)f2bf(ae.x); afrag[5] = (short)f2bf(ae.y);
            afrag[6] = (short)0x3F80;   // 1.0 bf16
        }

        float v[16];
        #pragma unroll
        for (int i = 0; i < 16; ++i) v[i] = 0.0f;

        #pragma unroll
        for (int t = 0; t < 16; ++t) {
            f32x4 acc = (f32x4){0.0f, 0.0f, 0.0f, 0.0f};
            acc = __builtin_amdgcn_mfma_f32_16x16x32_bf16(afrag, bfrag[t], acc, 0, 0, 0);
            const int h = t >> 2;
            #pragma unroll
            for (int r = 0; r < 4; ++r) {
                float z = acc[r];
                v[r * 4 + h] = fmaf(a6[t], z, fmaf(a4[t], fabsf(z), v[r * 4 + h]));
            }
        }

        // reduce-scatter butterfly: 16 values over the 16 lanes of each group
        #pragma unroll
        for (int m = 8; m >= 1; m >>= 1) {
            #pragma unroll
            for (int i = 0; i < 8; ++i) {
                if (i < m) {
                    float send = (lo & m) ? v[i] : v[i + m];
                    float got = __shfl_xor(send, m);
                    float keep = (lo & m) ? v[i + m] : v[i];
                    v[i] = keep + got;
                }
            }
        }
        // lane lo holds total for idx=lo: edge r=lo>>2 (within group), head h=lo&3
        const int g = lane >> 4;
        alpha1[(size_t)(lo & 3) * E_AUG + e0 + 4 * g + (lo >> 2)] = v[0];
    }
}

// ---------------- Fused: l1 softmax + h build + bf16 MFMA projections ----------------

__global__ __launch_bounds__(256) void l1out_fused_kernel(
    const float* __restrict__ x, const int* __restrict__ offs,
    const int* __restrict__ e_src, const float* __restrict__ alpha1,
    const float4* __restrict__ wpk4, const ushort16* __restrict__ Wt,
    const float* __restrict__ b2l, const float* __restrict__ b2r,
    ushort16* __restrict__ xl2b, ushort16* __restrict__ xr2b) {
    __shared__ short hlds[64 * 256];    // 32 KB bf16 h tile
    __shared__ float4 swpk[256];        // 4 KB build coeffs
    const int tid = threadIdx.x;
    const int n0 = blockIdx.x * 64;
    const int lane = tid & 63, w = tid >> 6;

    swpk[tid] = wpk4[tid];

    // ---- phase 0: online softmax for (node, head) ----
    const int nl = tid >> 2, head = tid & 3;
    const int node = n0 + nl;
    float S1 = 0.0f, S2 = 0.0f;
    if (node < N_NODES) {
        const int beg = offs[node], end = offs[node + 1];
        const float* ap = alpha1 + (size_t)head * E_AUG;
        float amax = -1e30f, den = 0.0f, s1 = 0.0f, s2 = 0.0f;
        for (int e = beg; e < end; ++e) {
            float lg = ap[e];
            int s = e_src[e];
            float2 xs = *(const float2*)&x[2 * s];
            float m = fmaxf(amax, lg);
            float sc = __expf(amax - m);
            float wt = __expf(lg - m);
            den = fmaf(den, sc, wt);
            s1 = fmaf(s1, sc, wt * xs.x);
            s2 = fmaf(s2, sc, wt * xs.y);
            amax = m;
        }
        float inv = 1.0f / (den + 1e-16f);
        S1 = s1 * inv;
        S2 = s2 * inv;
    }
    __syncthreads();   // swpk ready

    // ---- phase 1: build h slice (head segment of 64 channels) ----
    {
        const int kseg = head * 64;
        const int swz = (nl & 7) << 3;
        for (int i = 0; i < 8; ++i) {
            short8v hv;
            #pragma unroll
            for (int j = 0; j < 8; ++j) {
                float4 wv = swpk[kseg + i * 8 + j];
                float g = fmaf(wv.x, S1, fmaf(wv.y, S2, wv.z));
                g = g > 0.0f ? g : (__expf(g) - 1.0f);
                hv[j] = (short)f2bf(g);
            }
            *(short8v*)&hlds[(nl * 256 + kseg + i * 8) ^ swz] = hv;
        }
    }

    // ---- B fragments ----
    short8v bfrag[2][8];
    {
        const int bc = w * 32 + (lane & 15);
        const int k0 = (lane >> 4) * 8;
        #pragma unroll
        for (int ct = 0; ct < 2; ++ct)
            #pragma unroll
            for (int kb = 0; kb < 8; ++kb)
                bfrag[ct][kb] = *(const short8v*)&Wt[(size_t)(bc + ct * 16) * 256 + kb * 32 + k0];
    }
    __syncthreads();

    // ---- phase 2: MFMA 4 row-tiles x 2 col-tiles x 8 k-blocks ----
    f32x4 acc[4][2];
    #pragma unroll
    for (int rt = 0; rt < 4; ++rt)
        #pragma unroll
        for (int ct = 0; ct < 2; ++ct)
            acc[rt][ct] = (f32x4){0.0f, 0.0f, 0.0f, 0.0f};

    const int arow = lane & 15, ak0 = (lane >> 4) * 8;
    #pragma unroll
    for (int rt = 0; rt < 4; ++rt) {
        const int n = rt * 16 + arow;
        const int swz = (n & 7) << 3;
        #pragma unroll
        for (int kb = 0; kb < 8; ++kb) {
            short8v a = *(const short8v*)&hlds[(n * 256 + kb * 32 + ak0) ^ swz];
            acc[rt][0] = __builtin_amdgcn_mfma_f32_16x16x32_bf16(a, bfrag[0][kb], acc[rt][0], 0, 0, 0);
            acc[rt][1] = __builtin_amdgcn_mfma_f32_16x16x32_bf16(a, bfrag[1][kb], acc[rt][1], 0, 0, 0);
        }
    }

    // ---- epilogue: bf16 store ----
    #pragma unroll
    for (int ct = 0; ct < 2; ++ct) {
        const int c = w * 32 + ct * 16 + (lane & 15);
        const bool isL = (c < 64);
        const int cc = isL ? c : c - 64;
        const float bias = isL ? b2l[cc] : b2r[cc];
        ushort16* dst = isL ? xl2b : xr2b;
        #pragma unroll
        for (int rt = 0; rt < 4; ++rt)
            #pragma unroll
            for (int r = 0; r < 4; ++r) {
                int nn = n0 + rt * 16 + (lane >> 4) * 4 + r;
                if (nn < N_NODES) dst[nn * 64 + cc] = f2bf(acc[rt][ct][r] + bias);
            }
    }
}

// ---------------- Layer 2 logits: 4 edges per wave, 16-lane dot ----------------

__global__ __launch_bounds__(256) void l2_logit_kernel(
    const ushort16* __restrict__ xl2b, const ushort16* __restrict__ xr2b,
    const int* __restrict__ e_src, const int* __restrict__ e_dst,
    const float* __restrict__ e_ea,
    const float* __restrict__ W2e, const float* __restrict__ att2,
    float* __restrict__ alpha2) {
    __shared__ float sWe[128], satt[64];
    const int tid = threadIdx.x;
    if (tid < 128) sWe[tid] = W2e[tid];
    if (tid < 64) satt[tid] = att2[tid];
    __syncthreads();

    const int lane = tid & 63, w = tid >> 6;
    const int e = blockIdx.x * 16 + w * 4 + (lane >> 4);   // E_AUG % 16 == 0

    const int s = e_src[e], d = e_dst[e];
    const float2 ae = *(const float2*)&e_ea[2 * e];
    const int cl = lane & 15;

    float acc = 0.0f;
    #pragma unroll
    for (int q = 0; q < 4; ++q) {
        const int c = cl + q * 16;
        const float xl = bf2f(xl2b[s * 64 + c]);
        const float xr = bf2f(xr2b[d * 64 + c]);
        float t = xl + xr + fmaf(ae.x, sWe[c], ae.y * sWe[64 + c]);
        t = t > 0.0f ? t : 0.2f * t;
        acc = fmaf(t, satt[c], acc);
    }
    #pragma unroll
    for (int off = 8; off; off >>= 1) acc += __shfl_xor(acc, off);
    if (cl == 0) alpha2[e] = acc;
}

// ---------------- Layer 2 aggregation: wave per node, no shuffles ----------------

__global__ __launch_bounds__(256) void l2_aggr_kernel(
    const ushort16* __restrict__ xl2b, const int* __restrict__ offs,
    const int* __restrict__ e_src, const float* __restrict__ alpha2,
    float* __restrict__ pblock) {
    __shared__ float sp[4][64];
    const int tid = threadIdx.x;
    const int l = tid & 63, w = tid >> 6;
    const int n = blockIdx.x * 4 + w;
    const int beg = offs[n], end = offs[n + 1];

    float amax = -1e30f, den = 0.0f, acc = 0.0f;
    int e = beg;
    for (; e + 4 <= end; e += 4) {
        const float4 a4 = *(const float4*)&alpha2[e];
        const int s0 = e_src[e], s1 = e_src[e + 1], s2 = e_src[e + 2], s3 = e_src[e + 3];
        const float xl0 = bf2f(xl2b[s0 * 64 + l]);
        const float xl1 = bf2f(xl2b[s1 * 64 + l]);
        const float xl2 = bf2f(xl2b[s2 * 64 + l]);
        const float xl3 = bf2f(xl2b[s3 * 64 + l]);
        const float mnew = fmaxf(fmaxf(amax, fmaxf(a4.x, a4.y)), fmaxf(a4.z, a4.w));
        const float sc = __expf(amax - mnew);
        const float w0 = __expf(a4.x - mnew), w1 = __expf(a4.y - mnew);
        const float w2 = __expf(a4.z - mnew), w3 = __expf(a4.w - mnew);
        den = fmaf(den, sc, (w0 + w1) + (w2 + w3));
        acc = fmaf(acc, sc, fmaf(w0, xl0, fmaf(w1, xl1, fmaf(w2, xl2, w3 * xl3))));
        amax = mnew;
    }
    for (; e < end; ++e) {
        const float a = alpha2[e];
        const int s = e_src[e];
        const float xl = bf2f(xl2b[s * 64 + l]);
        const float mnew = fmaxf(amax, a);
        const float sc = __expf(amax - mnew);
        const float ww = __expf(a - mnew);
        den = fmaf(den, sc, ww);
        acc = fmaf(acc, sc, ww * xl);
        amax = mnew;
    }
    sp[w][l] = acc / (den + 1e-16f);
    __syncthreads();
    if (tid < 64) {
        float v = sp[0][l] + sp[1][l] + sp[2][l] + sp[3][l];
        pblock[blockIdx.x * 64 + l] = v;
    }
}

// ---------------- final pool ----------------

__global__ __launch_bounds__(256) void pool_final_kernel(const float* __restrict__ pblock,
                                                         const float* __restrict__ bias2,
                                                         float* __restrict__ d_out) {
    __shared__ float s[256];
    int tid = threadIdx.x;
    int l = tid & 63, q = tid >> 6;
    float local = 0.0f;
    for (int r = blockIdx.x * 4 + q; r < 12500; r += 64 * 4)
        local += pblock[r * 64 + l];
    s[tid] = local;
    __syncthreads();
    if (tid < 64) {
        float v = s[tid] + s[tid + 64] + s[tid + 128] + s[tid + 192];
        atomicAdd(&d_out[tid], v * (1.0f / N_NODES));
        if (blockIdx.x == 0) atomicAdd(&d_out[tid], bias2[tid]);
    }
}

// ---------------- Host launch ----------------

extern "C" void kernel_launch(void* const* d_in, const int* in_sizes, int n_in,
                              void* d_out, int out_size, void* d_ws, size_t ws_size,
                              hipStream_t stream) {
    const float* x     = (const float*)d_in[0];
    const float* eattr = (const float*)d_in[1];
    const float* W1l   = (const float*)d_in[2];
    const float* b1l   = (const float*)d_in[3];
    const float* W1r   = (const float*)d_in[4];
    const float* b1r   = (const float*)d_in[5];
    const float* W1e   = (const float*)d_in[6];
    const float* att1  = (const float*)d_in[7];
    const float* bias1 = (const float*)d_in[8];
    const float* W2l   = (const float*)d_in[9];
    const float* b2l   = (const float*)d_in[10];
    const float* W2r   = (const float*)d_in[11];
    const float* b2r   = (const float*)d_in[12];
    const float* W2e   = (const float*)d_in[13];
    const float* att2  = (const float*)d_in[14];
    const float* bias2 = (const float*)d_in[15];
    const int*   ei    = (const int*)d_in[16];
    float* out = (float*)d_out;

    char* p = (char*)d_ws;
    auto alloc = [&](size_t bytes) -> void* {
        void* r = (void*)p;
        p += (bytes + 255) & ~(size_t)255;
        return r;
    };
    int*   deg    = (int*)alloc(N_NODES * 4);
    int*   cnt    = (int*)alloc(N_NODES * 4);
    size_t zlen   = (size_t)((char*)cnt - (char*)deg) + ((N_NODES * 4 + 255) & ~(size_t)255);
    int*   offs   = (int*)alloc((N_NODES + 1) * 4);
    int*   bsum   = (int*)alloc(256 * 4);
    int*   e_src  = (int*)alloc(E_AUG * 4);
    int*   e_dst  = (int*)alloc(E_AUG * 4);
    float* e_ea   = (float*)alloc((size_t)E_AUG * 2 * 4);
    float* alpha1 = (float*)alloc((size_t)E_AUG * 4 * 4);
    float* alpha2 = (float*)alloc((size_t)E_AUG * 4);
    float* Wbt    = (float*)alloc(8 * 256 * 4);
    float4* wpk4  = (float4*)alloc(256 * 16);
    ushort16* Wt  = (ushort16*)alloc(128 * 256 * 2);
    ushort16* xl2b = (ushort16*)alloc((size_t)N_NODES * C2 * 2);
    ushort16* xr2b = (ushort16*)alloc((size_t)N_NODES * C2 * 2);
    float* pblock = (float*)alloc((size_t)12500 * 64 * 4);

    hipMemsetAsync(deg, 0, zlen, stream);
    hipMemsetAsync(d_out, 0, 64 * 4, stream);

    deg_pack_kernel<<<PACK_BLOCKS + HIST_BLOCKS, 256, 0, stream>>>(
        ei, W1l, b1l, W1r, b1r, W1e, att1, bias1, W2l, W2r,
        Wbt, wpk4, Wt, deg);

    int nb = (N_NODES + 255) / 256;   // 196
    scan1_kernel<<<nb, 256, 0, stream>>>(deg, offs, bsum);
    scan23_kernel<<<nb, 256, 0, stream>>>(offs, bsum, nb);
    scatter_kernel<<<(N_EDGES + 255) / 256, 256, 0, stream>>>(ei, eattr, offs, cnt,
                                                              e_src, e_dst, e_ea);
    loop_fill_kernel<<<nb, 256, 0, stream>>>(offs, e_src, e_dst, e_ea);

    l1_alpha_kernel<<<768, 256, 0, stream>>>(x, e_src, e_dst, e_ea, Wbt, att1, alpha1);

    l1out_fused_kernel<<<(N_NODES + 63) / 64, 256, 0, stream>>>(x, offs, e_src, alpha1,
                                                                wpk4, Wt, b2l, b2r,
                                                                xl2b, xr2b);

    l2_logit_kernel<<<E_AUG / 16, 256, 0, stream>>>(xl2b, xr2b, e_src, e_dst, e_ea,
                                                    W2e, att2, alpha2);

    l2_aggr_kernel<<<N_NODES / 4, 256, 0, stream>>>(xl2b, offs, e_src, alpha2, pblock);

    pool_final_kernel<<<64, 256, 0, stream>>>(pblock, bias2, out);
}

// Round 9
// 252.149 us; speedup vs baseline: 1.2049x; 1.2049x over previous
//
#include <hip/hip_runtime.h>
#include <hip/hip_bf16.h>

#define N_NODES 50000
#define N_EDGES 500000
#define E_AUG   (N_EDGES + N_NODES)   // 550000 (divisible by 16)
#define NH1 4
#define HID 64
#define C2  64

typedef unsigned int uint32;
typedef unsigned short ushort16;
typedef __attribute__((ext_vector_type(8))) short short8v;
typedef __attribute__((ext_vector_type(4))) float f32x4;

__device__ __forceinline__ ushort16 f2bf(float f) {
    union { float f; uint32 u; } v; v.f = f;
    uint32 u = v.u + (0x7FFFu + ((v.u >> 16) & 1u));   // RNE
    return (ushort16)(u >> 16);
}
__device__ __forceinline__ float bf2f(ushort16 h) {
    union { uint32 u; float f; } v; v.u = ((uint32)h) << 16;
    return v.f;
}

// ---------------- fused pack + degree histogram ----------------
// blocks [0,128): weight packing; blocks [128,...): int histogram (4 edges/thread)
// Wpack[c][h][8] = {Wl0,Wl1,Wr0,Wr1,We0,We1, b1l+b1r, 0.4*att1} for column hc=h*64+c
// Apack[h][8]    = 0.6 * sum_c att1[h,c] * {...}  (lrelu linear part)
// wpk4[k] = {W1l[0][k], W1l[1][k], b1l[k]+bias1[k], 0}  (h-build coeffs)
// Wt[c][k] bf16, c<64 -> W2l[k][c], else W2r[k][c-64]   (B operand, l1out MFMA)

#define PACK_BLOCKS 128
#define HIST_BLOCKS ((N_EDGES / 4 + 255) / 256)   // 489

__global__ void deg_pack_kernel(const int* __restrict__ ei,
                                const float* __restrict__ W1l, const float* __restrict__ b1l,
                                const float* __restrict__ W1r, const float* __restrict__ b1r,
                                const float* __restrict__ W1e, const float* __restrict__ att1,
                                const float* __restrict__ bias1,
                                const float* __restrict__ W2l, const float* __restrict__ W2r,
                                float* __restrict__ Wpack, float* __restrict__ Apack,
                                float4* __restrict__ wpk4, ushort16* __restrict__ Wt,
                                int* __restrict__ deg) {
    const int tid = threadIdx.x;
    if (blockIdx.x < PACK_BLOCKS) {
        int t = blockIdx.x * 256 + tid;
        if (blockIdx.x == 0) {
            if (tid < 256) {
                int h = tid >> 6, hc = tid;
                float* wp = &Wpack[((tid & 63) * 4 + h) * 8];
                wp[0] = W1l[hc];       wp[1] = W1l[256 + hc];
                wp[2] = W1r[hc];       wp[3] = W1r[256 + hc];
                wp[4] = W1e[hc];       wp[5] = W1e[256 + hc];
                wp[6] = b1l[hc] + b1r[hc];
                wp[7] = 0.4f * att1[hc];
                wpk4[hc] = make_float4(W1l[hc], W1l[256 + hc], b1l[hc] + bias1[hc], 0.0f);
            }
            if (tid < 28) {
                int h = tid / 7, comp = tid % 7;
                float s = 0.0f;
                for (int c = 0; c < 64; ++c) {
                    int hc = h * 64 + c;
                    float m;
                    switch (comp) {
                        case 0: m = W1l[hc]; break;
                        case 1: m = W1l[256 + hc]; break;
                        case 2: m = W1r[hc]; break;
                        case 3: m = W1r[256 + hc]; break;
                        case 4: m = W1e[hc]; break;
                        case 5: m = W1e[256 + hc]; break;
                        default: m = b1l[hc] + b1r[hc]; break;
                    }
                    s += att1[hc] * m;
                }
                Apack[h * 8 + comp] = 0.6f * s;
            }
        }
        if (t < 128 * 256) {
            int c = t & 127, k = t >> 7;
            float w = (c < 64) ? W2l[k * 64 + c] : W2r[k * 64 + (c - 64)];
            Wt[c * 256 + k] = f2bf(w);
        }
    } else {
        const int e0 = ((blockIdx.x - PACK_BLOCKS) * 256 + tid) * 4;
        if (e0 < N_EDGES) {   // N_EDGES % 4 == 0
            const int4 d4 = *(const int4*)&ei[N_EDGES + e0];
            atomicAdd(&deg[d4.x], 1);
            atomicAdd(&deg[d4.y], 1);
            atomicAdd(&deg[d4.z], 1);
            atomicAdd(&deg[d4.w], 1);
        }
    }
}

// ---------------- CSR scans ----------------

__global__ void scan1_kernel(const int* __restrict__ deg, int* __restrict__ offs,
                             int* __restrict__ bsum) {
    __shared__ int s[256];
    int tid = threadIdx.x;
    int i = blockIdx.x * 256 + tid;
    int v = (i < N_NODES) ? (deg[i] + 1) : 0;   // +1 reserved self-loop slot
    s[tid] = v;
    __syncthreads();
    for (int off = 1; off < 256; off <<= 1) {
        int t = (tid >= off) ? s[tid - off] : 0;
        __syncthreads();
        s[tid] += t;
        __syncthreads();
    }
    if (i < N_NODES) offs[i + 1] = s[tid];
    if (tid == 255) bsum[blockIdx.x] = s[255];
}

__global__ void scan23_kernel(int* __restrict__ offs, const int* __restrict__ bsum, int nb) {
    __shared__ int s[256];
    int tid = threadIdx.x;
    int b = blockIdx.x;
    s[tid] = (tid < nb && tid < b) ? bsum[tid] : 0;
    __syncthreads();
    for (int off = 128; off; off >>= 1) {
        if (tid < off) s[tid] += s[tid + off];
        __syncthreads();
    }
    int base = s[0];
    int i = b * 256 + tid;
    if (i < N_NODES) offs[i + 1] += base;
    if (i == 0) offs[0] = 0;
}

// ---------------- scatter: packed edge record {s, d, a0, a1} (one 16B store) ----

__global__ void scatter_kernel(const int* __restrict__ ei, const float* __restrict__ ea,
                               const int* __restrict__ offs, int* __restrict__ cnt,
                               int4* __restrict__ epk, int* __restrict__ e_src) {
    int e = blockIdx.x * 256 + threadIdx.x;
    if (e >= N_EDGES) return;
    int s = ei[e], d = ei[N_EDGES + e];
    float2 a = *(const float2*)&ea[2 * e];
    int pos = offs[d] + 1 + atomicAdd(&cnt[d], 1);
    int4 v;
    v.x = s; v.y = d;
    v.z = __float_as_int(a.x); v.w = __float_as_int(a.y);
    epk[pos] = v;
    e_src[pos] = s;
}

// ---------------- self-loop fill: mean edge_attr over node's real edges ----------

__global__ void loop_fill_kernel(const int* __restrict__ offs,
                                 int4* __restrict__ epk, int* __restrict__ e_src) {
    int n = blockIdx.x * 256 + threadIdx.x;
    if (n >= N_NODES) return;
    int beg = offs[n], end = offs[n + 1];
    float s0 = 0.0f, s1 = 0.0f;
    for (int e = beg + 1; e < end; ++e) {
        int4 v = epk[e];
        s0 += __int_as_float(v.z);
        s1 += __int_as_float(v.w);
    }
    float inv = 1.0f / (float)max(end - beg - 1, 1);
    int4 v;
    v.x = n; v.y = n;
    v.z = __float_as_int(s0 * inv); v.w = __float_as_int(s1 * inv);
    epk[beg] = v;
    e_src[beg] = n;
}

// ---------------- Layer 1 alpha: edge-parallel VALU, 2 edges/thread ----------------
// p_h = A_h·[u,1] + sum_c 0.4*att_hc*|z_hc|,  z = W·u + b   (lrelu = 0.6z + 0.4|z|)
// alpha1 SoA: plane h at alpha1[h*E_AUG + e]

__global__ __launch_bounds__(256) void l1_alpha_kernel(
    const float* __restrict__ x, const int4* __restrict__ epk,
    const float* __restrict__ Wpack, const float* __restrict__ Apack,
    float* __restrict__ alpha1) {
    __shared__ float sWp[2048];
    __shared__ float sA[32];
    const int tid = threadIdx.x;
    for (int i = tid; i < 2048; i += 256) sWp[i] = Wpack[i];
    if (tid < 32) sA[tid] = Apack[tid];
    __syncthreads();

    const int e0 = (blockIdx.x * 256 + tid) * 2;
    if (e0 >= E_AUG) return;   // E_AUG even -> full pairs

    const int4 v0 = epk[e0];
    const int4 v1 = epk[e0 + 1];

    float u0[2], u1[2], u2[2], u3[2], u4[2], u5[2];
    {
        const float2 xs0 = *(const float2*)&x[2 * v0.x];
        const float2 xd0 = *(const float2*)&x[2 * v0.y];
        const float2 xs1 = *(const float2*)&x[2 * v1.x];
        const float2 xd1 = *(const float2*)&x[2 * v1.y];
        u0[0] = xs0.x; u1[0] = xs0.y; u2[0] = xd0.x; u3[0] = xd0.y;
        u4[0] = __int_as_float(v0.z); u5[0] = __int_as_float(v0.w);
        u0[1] = xs1.x; u1[1] = xs1.y; u2[1] = xd1.x; u3[1] = xd1.y;
        u4[1] = __int_as_float(v1.z); u5[1] = __int_as_float(v1.w);
    }

    float p[4][2];
    #pragma unroll
    for (int h = 0; h < 4; ++h) {
        const float a0 = sA[h * 8], a1 = sA[h * 8 + 1], a2 = sA[h * 8 + 2],
                    a3 = sA[h * 8 + 3], a4 = sA[h * 8 + 4], a5 = sA[h * 8 + 5],
                    a6 = sA[h * 8 + 6];
        #pragma unroll
        for (int j = 0; j < 2; ++j)
            p[h][j] = fmaf(u0[j], a0, fmaf(u1[j], a1, fmaf(u2[j], a2,
                      fmaf(u3[j], a3, fmaf(u4[j], a4, fmaf(u5[j], a5, a6))))));
    }

    for (int c = 0; c < 64; ++c) {
        const float* wp = &sWp[c * 32];
        #pragma unroll
        for (int h = 0; h < 4; ++h) {
            const float4 wa = *(const float4*)&wp[h * 8];
            const float4 wb = *(const float4*)&wp[h * 8 + 4];
            #pragma unroll
            for (int j = 0; j < 2; ++j) {
                float t = fmaf(u0[j], wa.x,
                          fmaf(u1[j], wa.y,
                          fmaf(u2[j], wa.z,
                          fmaf(u3[j], wa.w,
                          fmaf(u4[j], wb.x,
                          fmaf(u5[j], wb.y, wb.z))))));
                p[h][j] = fmaf(fabsf(t), wb.w, p[h][j]);
            }
        }
    }

    #pragma unroll
    for (int h = 0; h < 4; ++h)
        *(float2*)&alpha1[(size_t)h * E_AUG + e0] = make_float2(p[h][0], p[h][1]);
}

// ---------------- Fused: l1 softmax + h build + bf16 MFMA projections ----------------

__global__ __launch_bounds__(256) void l1out_fused_kernel(
    const float* __restrict__ x, const int* __restrict__ offs,
    const int* __restrict__ e_src, const float* __restrict__ alpha1,
    const float4* __restrict__ wpk4, const ushort16* __restrict__ Wt,
    const float* __restrict__ b2l, const float* __restrict__ b2r,
    ushort16* __restrict__ xl2b, ushort16* __restrict__ xr2b) {
    __shared__ short hlds[64 * 256];    // 32 KB bf16 h tile
    __shared__ float4 swpk[256];        // 4 KB build coeffs
    const int tid = threadIdx.x;
    const int n0 = blockIdx.x * 64;
    const int lane = tid & 63, w = tid >> 6;

    swpk[tid] = wpk4[tid];

    // ---- phase 0: online softmax for (node, head) ----
    const int nl = tid >> 2, head = tid & 3;
    const int node = n0 + nl;
    float S1 = 0.0f, S2 = 0.0f;
    if (node < N_NODES) {
        const int beg = offs[node], end = offs[node + 1];
        const float* ap = alpha1 + (size_t)head * E_AUG;
        float amax = -1e30f, den = 0.0f, s1 = 0.0f, s2 = 0.0f;
        for (int e = beg; e < end; ++e) {
            float lg = ap[e];
            int s = e_src[e];
            float2 xs = *(const float2*)&x[2 * s];
            float m = fmaxf(amax, lg);
            float sc = __expf(amax - m);
            float wt = __expf(lg - m);
            den = fmaf(den, sc, wt);
            s1 = fmaf(s1, sc, wt * xs.x);
            s2 = fmaf(s2, sc, wt * xs.y);
            amax = m;
        }
        float inv = 1.0f / (den + 1e-16f);
        S1 = s1 * inv;
        S2 = s2 * inv;
    }
    __syncthreads();   // swpk ready

    // ---- phase 1: build h slice (head segment of 64 channels) ----
    {
        const int kseg = head * 64;
        const int swz = (nl & 7) << 3;
        for (int i = 0; i < 8; ++i) {
            short8v hv;
            #pragma unroll
            for (int j = 0; j < 8; ++j) {
                float4 wv = swpk[kseg + i * 8 + j];
                float g = fmaf(wv.x, S1, fmaf(wv.y, S2, wv.z));
                g = g > 0.0f ? g : (__expf(g) - 1.0f);
                hv[j] = (short)f2bf(g);
            }
            *(short8v*)&hlds[(nl * 256 + kseg + i * 8) ^ swz] = hv;
        }
    }

    // ---- B fragments ----
    short8v bfrag[2][8];
    {
        const int bc = w * 32 + (lane & 15);
        const int k0 = (lane >> 4) * 8;
        #pragma unroll
        for (int ct = 0; ct < 2; ++ct)
            #pragma unroll
            for (int kb = 0; kb < 8; ++kb)
                bfrag[ct][kb] = *(const short8v*)&Wt[(size_t)(bc + ct * 16) * 256 + kb * 32 + k0];
    }
    __syncthreads();

    // ---- phase 2: MFMA 4 row-tiles x 2 col-tiles x 8 k-blocks ----
    f32x4 acc[4][2];
    #pragma unroll
    for (int rt = 0; rt < 4; ++rt)
        #pragma unroll
        for (int ct = 0; ct < 2; ++ct)
            acc[rt][ct] = (f32x4){0.0f, 0.0f, 0.0f, 0.0f};

    const int arow = lane & 15, ak0 = (lane >> 4) * 8;
    #pragma unroll
    for (int rt = 0; rt < 4; ++rt) {
        const int n = rt * 16 + arow;
        const int swz = (n & 7) << 3;
        #pragma unroll
        for (int kb = 0; kb < 8; ++kb) {
            short8v a = *(const short8v*)&hlds[(n * 256 + kb * 32 + ak0) ^ swz];
            acc[rt][0] = __builtin_amdgcn_mfma_f32_16x16x32_bf16(a, bfrag[0][kb], acc[rt][0], 0, 0, 0);
            acc[rt][1] = __builtin_amdgcn_mfma_f32_16x16x32_bf16(a, bfrag[1][kb], acc[rt][1], 0, 0, 0);
        }
    }

    // ---- epilogue: bf16 store ----
    #pragma unroll
    for (int ct = 0; ct < 2; ++ct) {
        const int c = w * 32 + ct * 16 + (lane & 15);
        const bool isL = (c < 64);
        const int cc = isL ? c : c - 64;
        const float bias = isL ? b2l[cc] : b2r[cc];
        ushort16* dst = isL ? xl2b : xr2b;
        #pragma unroll
        for (int rt = 0; rt < 4; ++rt)
            #pragma unroll
            for (int r = 0; r < 4; ++r) {
                int nn = n0 + rt * 16 + (lane >> 4) * 4 + r;
                if (nn < N_NODES) dst[nn * 64 + cc] = f2bf(acc[rt][ct][r] + bias);
            }
    }
}

// ---------------- Layer 2 logits: 4 edges per wave, 16-lane dot ----------------

__global__ __launch_bounds__(256) void l2_logit_kernel(
    const ushort16* __restrict__ xl2b, const ushort16* __restrict__ xr2b,
    const int4* __restrict__ epk,
    const float* __restrict__ W2e, const float* __restrict__ att2,
    float* __restrict__ alpha2) {
    __shared__ float sWe[128], satt[64];
    const int tid = threadIdx.x;
    if (tid < 128) sWe[tid] = W2e[tid];
    if (tid < 64) satt[tid] = att2[tid];
    __syncthreads();

    const int lane = tid & 63, w = tid >> 6;
    const int e = blockIdx.x * 16 + w * 4 + (lane >> 4);   // E_AUG % 16 == 0

    const int4 v = epk[e];
    const int s = v.x, d = v.y;
    const float ae0 = __int_as_float(v.z), ae1 = __int_as_float(v.w);
    const int cl = lane & 15;

    float acc = 0.0f;
    #pragma unroll
    for (int q = 0; q < 4; ++q) {
        const int c = cl + q * 16;
        const float xl = bf2f(xl2b[s * 64 + c]);
        const float xr = bf2f(xr2b[d * 64 + c]);
        float t = xl + xr + fmaf(ae0, sWe[c], ae1 * sWe[64 + c]);
        t = t > 0.0f ? t : 0.2f * t;
        acc = fmaf(t, satt[c], acc);
    }
    #pragma unroll
    for (int off = 8; off; off >>= 1) acc += __shfl_xor(acc, off);
    if (cl == 0) alpha2[e] = acc;
}

// ---------------- Layer 2 aggregation: wave per node, no shuffles ----------------

__global__ __launch_bounds__(256) void l2_aggr_kernel(
    const ushort16* __restrict__ xl2b, const int* __restrict__ offs,
    const int* __restrict__ e_src, const float* __restrict__ alpha2,
    float* __restrict__ pblock) {
    __shared__ float sp[4][64];
    const int tid = threadIdx.x;
    const int l = tid & 63, w = tid >> 6;
    const int n = blockIdx.x * 4 + w;
    const int beg = offs[n], end = offs[n + 1];

    float amax = -1e30f, den = 0.0f, acc = 0.0f;
    int e = beg;
    for (; e + 4 <= end; e += 4) {
        const float4 a4 = *(const float4*)&alpha2[e];
        const int s0 = e_src[e], s1 = e_src[e + 1], s2 = e_src[e + 2], s3 = e_src[e + 3];
        const float xl0 = bf2f(xl2b[s0 * 64 + l]);
        const float xl1 = bf2f(xl2b[s1 * 64 + l]);
        const float xl2 = bf2f(xl2b[s2 * 64 + l]);
        const float xl3 = bf2f(xl2b[s3 * 64 + l]);
        const float mnew = fmaxf(fmaxf(amax, fmaxf(a4.x, a4.y)), fmaxf(a4.z, a4.w));
        const float sc = __expf(amax - mnew);
        const float w0 = __expf(a4.x - mnew), w1 = __expf(a4.y - mnew);
        const float w2 = __expf(a4.z - mnew), w3 = __expf(a4.w - mnew);
        den = fmaf(den, sc, (w0 + w1) + (w2 + w3));
        acc = fmaf(acc, sc, fmaf(w0, xl0, fmaf(w1, xl1, fmaf(w2, xl2, w3 * xl3))));
        amax = mnew;
    }
    for (; e < end; ++e) {
        const float a = alpha2[e];
        const int s = e_src[e];
        const float xl = bf2f(xl2b[s * 64 + l]);
        const float mnew = fmaxf(amax, a);
        const float sc = __expf(amax - mnew);
        const float ww = __expf(a - mnew);
        den = fmaf(den, sc, ww);
        acc = fmaf(acc, sc, ww * xl);
        amax = mnew;
    }
    sp[w][l] = acc / (den + 1e-16f);
    __syncthreads();
    if (tid < 64) {
        float v = sp[0][l] + sp[1][l] + sp[2][l] + sp[3][l];
        pblock[blockIdx.x * 64 + l] = v;
    }
}

// ---------------- final pool ----------------

__global__ __launch_bounds__(256) void pool_final_kernel(const float* __restrict__ pblock,
                                                         const float* __restrict__ bias2,
                                                         float* __restrict__ d_out) {
    __shared__ float s[256];
    int tid = threadIdx.x;
    int l = tid & 63, q = tid >> 6;
    float local = 0.0f;
    for (int r = blockIdx.x * 4 + q; r < 12500; r += 64 * 4)
        local += pblock[r * 64 + l];
    s[tid] = local;
    __syncthreads();
    if (tid < 64) {
        float v = s[tid] + s[tid + 64] + s[tid + 128] + s[tid + 192];
        atomicAdd(&d_out[tid], v * (1.0f / N_NODES));
        if (blockIdx.x == 0) atomicAdd(&d_out[tid], bias2[tid]);
    }
}

// ---------------- Host launch ----------------

extern "C" void kernel_launch(void* const* d_in, const int* in_sizes, int n_in,
                              void* d_out, int out_size, void* d_ws, size_t ws_size,
                              hipStream_t stream) {
    const float* x     = (const float*)d_in[0];
    const float* eattr = (const float*)d_in[1];
    const float* W1l   = (const float*)d_in[2];
    const float* b1l   = (const float*)d_in[3];
    const float* W1r   = (const float*)d_in[4];
    const float* b1r   = (const float*)d_in[5];
    const float* W1e   = (const float*)d_in[6];
    const float* att1  = (const float*)d_in[7];
    const float* bias1 = (const float*)d_in[8];
    const float* W2l   = (const float*)d_in[9];
    const float* b2l   = (const float*)d_in[10];
    const float* W2r   = (const float*)d_in[11];
    const float* b2r   = (const float*)d_in[12];
    const float* W2e   = (const float*)d_in[13];
    const float* att2  = (const float*)d_in[14];
    const float* bias2 = (const float*)d_in[15];
    const int*   ei    = (const int*)d_in[16];
    float* out = (float*)d_out;

    char* p = (char*)d_ws;
    auto alloc = [&](size_t bytes) -> void* {
        void* r = (void*)p;
        p += (bytes + 255) & ~(size_t)255;
        return r;
    };
    int*   deg    = (int*)alloc(N_NODES * 4);
    int*   cnt    = (int*)alloc(N_NODES * 4);
    size_t zlen   = (size_t)((char*)cnt - (char*)deg) + ((N_NODES * 4 + 255) & ~(size_t)255);
    int*   offs   = (int*)alloc((N_NODES + 1) * 4);
    int*   bsum   = (int*)alloc(256 * 4);
    int4*  epk    = (int4*)alloc((size_t)E_AUG * 16);
    int*   e_src  = (int*)alloc(E_AUG * 4);
    float* alpha1 = (float*)alloc((size_t)E_AUG * 4 * 4);
    float* alpha2 = (float*)alloc((size_t)E_AUG * 4);
    float* Wpack  = (float*)alloc(256 * 8 * 4);
    float* Apack  = (float*)alloc(32 * 4);
    float4* wpk4  = (float4*)alloc(256 * 16);
    ushort16* Wt  = (ushort16*)alloc(128 * 256 * 2);
    ushort16* xl2b = (ushort16*)alloc((size_t)N_NODES * C2 * 2);
    ushort16* xr2b = (ushort16*)alloc((size_t)N_NODES * C2 * 2);
    float* pblock = (float*)alloc((size_t)12500 * 64 * 4);

    hipMemsetAsync(deg, 0, zlen, stream);
    hipMemsetAsync(d_out, 0, 64 * 4, stream);

    deg_pack_kernel<<<PACK_BLOCKS + HIST_BLOCKS, 256, 0, stream>>>(
        ei, W1l, b1l, W1r, b1r, W1e, att1, bias1, W2l, W2r,
        Wpack, Apack, wpk4, Wt, deg);

    int nb = (N_NODES + 255) / 256;   // 196
    scan1_kernel<<<nb, 256, 0, stream>>>(deg, offs, bsum);
    scan23_kernel<<<nb, 256, 0, stream>>>(offs, bsum, nb);
    scatter_kernel<<<(N_EDGES + 255) / 256, 256, 0, stream>>>(ei, eattr, offs, cnt,
                                                              epk, e_src);
    loop_fill_kernel<<<nb, 256, 0, stream>>>(offs, epk, e_src);

    l1_alpha_kernel<<<(E_AUG / 2 + 255) / 256, 256, 0, stream>>>(x, epk, Wpack, Apack,
                                                                 alpha1);

    l1out_fused_kernel<<<(N_NODES + 63) / 64, 256, 0, stream>>>(x, offs, e_src, alpha1,
                                                                wpk4, Wt, b2l, b2r,
                                                                xl2b, xr2b);

    l2_logit_kernel<<<E_AUG / 16, 256, 0, stream>>>(xl2b, xr2b, epk, W2e, att2, alpha2);

    l2_aggr_kernel<<<N_NODES / 4, 256, 0, stream>>>(xl2b, offs, e_src, alpha2, pblock);

    pool_final_kernel<<<64, 256, 0, stream>>>(pblock, bias2, out);
}

// Round 10
// 240.660 us; speedup vs baseline: 1.2625x; 1.0477x over previous
//
#include <hip/hip_runtime.h>
#include <hip/hip_bf16.h>

#define N_NODES 50000
#define N_EDGES 500000
#define E_AUG   (N_EDGES + N_NODES)   // 550000 (divisible by 16)
#define NH1 4
#define HID 64
#define C2  64

#define NBUCK 49                      // d >> 10  (50000/1024 -> 0..48)
#define BCAP  16384                   // per-bucket capacity (expect ~10240, +60 sigma)

typedef unsigned int uint32;
typedef unsigned short ushort16;
typedef __attribute__((ext_vector_type(8))) short short8v;
typedef __attribute__((ext_vector_type(4))) float f32x4;

__device__ __forceinline__ ushort16 f2bf(float f) {
    union { float f; uint32 u; } v; v.f = f;
    uint32 u = v.u + (0x7FFFu + ((v.u >> 16) & 1u));   // RNE
    return (ushort16)(u >> 16);
}
__device__ __forceinline__ float bf2f(ushort16 h) {
    union { uint32 u; float f; } v; v.u = ((uint32)h) << 16;
    return v.f;
}

// ---------------- pass1: weight pack + bucketed edge staging ----------------
// blocks [0,128): packing. blocks [128,...): 4 edges/thread, LDS-aggregated
// bucket append into stage[b*BCAP + ...]. No per-edge global atomics.

#define PACK_BLOCKS 128
#define HIST_BLOCKS ((N_EDGES / 4 + 255) / 256)   // 489

__global__ void pass1_kernel(const int* __restrict__ ei, const float* __restrict__ ea,
                             const float* __restrict__ W1l, const float* __restrict__ b1l,
                             const float* __restrict__ W1r, const float* __restrict__ b1r,
                             const float* __restrict__ W1e, const float* __restrict__ att1,
                             const float* __restrict__ bias1,
                             const float* __restrict__ W2l, const float* __restrict__ W2r,
                             float* __restrict__ Wpack, float* __restrict__ Apack,
                             float4* __restrict__ wpk4, ushort16* __restrict__ Wt,
                             int4* __restrict__ stage, int* __restrict__ bcnt) {
    const int tid = threadIdx.x;
    if (blockIdx.x < PACK_BLOCKS) {
        int t = blockIdx.x * 256 + tid;
        if (blockIdx.x == 0) {
            if (tid < 256) {
                int h = tid >> 6, hc = tid;
                float* wp = &Wpack[((tid & 63) * 4 + h) * 8];
                wp[0] = W1l[hc];       wp[1] = W1l[256 + hc];
                wp[2] = W1r[hc];       wp[3] = W1r[256 + hc];
                wp[4] = W1e[hc];       wp[5] = W1e[256 + hc];
                wp[6] = b1l[hc] + b1r[hc];
                wp[7] = 0.4f * att1[hc];
                wpk4[hc] = make_float4(W1l[hc], W1l[256 + hc], b1l[hc] + bias1[hc], 0.0f);
            }
            if (tid < 28) {
                int h = tid / 7, comp = tid % 7;
                float s = 0.0f;
                for (int c = 0; c < 64; ++c) {
                    int hc = h * 64 + c;
                    float m;
                    switch (comp) {
                        case 0: m = W1l[hc]; break;
                        case 1: m = W1l[256 + hc]; break;
                        case 2: m = W1r[hc]; break;
                        case 3: m = W1r[256 + hc]; break;
                        case 4: m = W1e[hc]; break;
                        case 5: m = W1e[256 + hc]; break;
                        default: m = b1l[hc] + b1r[hc]; break;
                    }
                    s += att1[hc] * m;
                }
                Apack[h * 8 + comp] = 0.6f * s;
            }
        }
        if (t < 128 * 256) {
            int c = t & 127, k = t >> 7;
            float w = (c < 64) ? W2l[k * 64 + c] : W2r[k * 64 + (c - 64)];
            Wt[c * 256 + k] = f2bf(w);
        }
    } else {
        __shared__ int lbc[NBUCK];
        __shared__ int lbase[NBUCK];
        if (tid < NBUCK) lbc[tid] = 0;
        __syncthreads();

        const int e0 = ((blockIdx.x - PACK_BLOCKS) * 256 + tid) * 4;
        int4 rec[4]; int bket[4], lofs[4];
        bool val[4];
        #pragma unroll
        for (int j = 0; j < 4; ++j) {
            const int e = e0 + j;
            val[j] = (e < N_EDGES);
            if (val[j]) {
                int s = ei[e], d = ei[N_EDGES + e];
                float2 a = *(const float2*)&ea[2 * e];
                rec[j].x = s; rec[j].y = d;
                rec[j].z = __float_as_int(a.x); rec[j].w = __float_as_int(a.y);
                bket[j] = d >> 10;
                lofs[j] = atomicAdd(&lbc[bket[j]], 1);
            }
        }
        __syncthreads();
        if (tid < NBUCK) lbase[tid] = lbc[tid] ? atomicAdd(&bcnt[tid], lbc[tid]) : 0;
        __syncthreads();
        #pragma unroll
        for (int j = 0; j < 4; ++j)
            if (val[j])
                stage[bket[j] * BCAP + lbase[bket[j]] + lofs[j]] = rec[j];
    }
}

// ---------------- degk: per-bucket LDS histogram -> deg (no global atomics) ----

__global__ void degk_kernel(const int4* __restrict__ stage, const int* __restrict__ bcnt,
                            int* __restrict__ deg) {
    __shared__ int bins[1024];
    const int tid = threadIdx.x;
    const int bk = blockIdx.x;
    for (int i = tid; i < 1024; i += 256) bins[i] = 0;
    __syncthreads();
    const int cnt = bcnt[bk];
    for (int i = tid; i < cnt; i += 256) {
        int d = stage[bk * BCAP + i].y;
        atomicAdd(&bins[d & 1023], 1);
    }
    __syncthreads();
    for (int i = tid; i < 1024; i += 256) {
        int n = bk * 1024 + i;
        if (n < N_NODES) deg[n] = bins[i];
    }
}

// ---------------- CSR scans ----------------

__global__ void scan1_kernel(const int* __restrict__ deg, int* __restrict__ offs,
                             int* __restrict__ bsum) {
    __shared__ int s[256];
    int tid = threadIdx.x;
    int i = blockIdx.x * 256 + tid;
    int v = (i < N_NODES) ? (deg[i] + 1) : 0;   // +1 reserved self-loop slot
    s[tid] = v;
    __syncthreads();
    for (int off = 1; off < 256; off <<= 1) {
        int t = (tid >= off) ? s[tid - off] : 0;
        __syncthreads();
        s[tid] += t;
        __syncthreads();
    }
    if (i < N_NODES) offs[i + 1] = s[tid];
    if (tid == 255) bsum[blockIdx.x] = s[255];
}

__global__ void scan23_kernel(int* __restrict__ offs, const int* __restrict__ bsum, int nb) {
    __shared__ int s[256];
    int tid = threadIdx.x;
    int b = blockIdx.x;
    s[tid] = (tid < nb && tid < b) ? bsum[tid] : 0;
    __syncthreads();
    for (int off = 128; off; off >>= 1) {
        if (tid < off) s[tid] += s[tid + off];
        __syncthreads();
    }
    int base = s[0];
    int i = b * 256 + tid;
    if (i < N_NODES) offs[i + 1] += base;
    if (i == 0) offs[0] = 0;
}

// ---------------- pass2: per-bucket counting scatter to final CSR ----------------
// Writes land in a ~200KB window per bucket -> L2-resident.

__global__ void pass2_kernel(const int4* __restrict__ stage, const int* __restrict__ bcnt,
                             const int* __restrict__ offs, int* __restrict__ cnt,
                             int4* __restrict__ epk, int* __restrict__ e_src) {
    const int tid = threadIdx.x;
    const int bk = blockIdx.x >> 2, slice = blockIdx.x & 3;
    const int n = bcnt[bk];
    const int chunk = (n + 3) >> 2;
    const int lo = slice * chunk, hi = min(n, lo + chunk);
    for (int i = lo + tid; i < hi; i += 256) {
        int4 r = stage[bk * BCAP + i];
        int pos = offs[r.y] + 1 + atomicAdd(&cnt[r.y], 1);
        epk[pos] = r;
        e_src[pos] = r.x;
    }
}

// ---------------- self-loop fill: mean edge_attr over node's real edges ----------

__global__ void loop_fill_kernel(const int* __restrict__ offs,
                                 int4* __restrict__ epk, int* __restrict__ e_src) {
    int n = blockIdx.x * 256 + threadIdx.x;
    if (n >= N_NODES) return;
    int beg = offs[n], end = offs[n + 1];
    float s0 = 0.0f, s1 = 0.0f;
    for (int e = beg + 1; e < end; ++e) {
        int4 v = epk[e];
        s0 += __int_as_float(v.z);
        s1 += __int_as_float(v.w);
    }
    float inv = 1.0f / (float)max(end - beg - 1, 1);
    int4 v;
    v.x = n; v.y = n;
    v.z = __float_as_int(s0 * inv); v.w = __float_as_int(s1 * inv);
    epk[beg] = v;
    e_src[beg] = n;
}

// ---------------- Layer 1 alpha: edge-parallel VALU, 2 edges/thread ----------------
// p_h = A_h·[u,1] + sum_c 0.4*att_hc*|z_hc|,  z = W·u + b   (lrelu = 0.6z + 0.4|z|)

__global__ __launch_bounds__(256) void l1_alpha_kernel(
    const float* __restrict__ x, const int4* __restrict__ epk,
    const float* __restrict__ Wpack, const float* __restrict__ Apack,
    float* __restrict__ alpha1) {
    __shared__ float sWp[2048];
    __shared__ float sA[32];
    const int tid = threadIdx.x;
    for (int i = tid; i < 2048; i += 256) sWp[i] = Wpack[i];
    if (tid < 32) sA[tid] = Apack[tid];
    __syncthreads();

    const int e0 = (blockIdx.x * 256 + tid) * 2;
    if (e0 >= E_AUG) return;   // E_AUG even -> full pairs

    const int4 v0 = epk[e0];
    const int4 v1 = epk[e0 + 1];

    float u0[2], u1[2], u2[2], u3[2], u4[2], u5[2];
    {
        const float2 xs0 = *(const float2*)&x[2 * v0.x];
        const float2 xd0 = *(const float2*)&x[2 * v0.y];
        const float2 xs1 = *(const float2*)&x[2 * v1.x];
        const float2 xd1 = *(const float2*)&x[2 * v1.y];
        u0[0] = xs0.x; u1[0] = xs0.y; u2[0] = xd0.x; u3[0] = xd0.y;
        u4[0] = __int_as_float(v0.z); u5[0] = __int_as_float(v0.w);
        u0[1] = xs1.x; u1[1] = xs1.y; u2[1] = xd1.x; u3[1] = xd1.y;
        u4[1] = __int_as_float(v1.z); u5[1] = __int_as_float(v1.w);
    }

    float p[4][2];
    #pragma unroll
    for (int h = 0; h < 4; ++h) {
        const float a0 = sA[h * 8], a1 = sA[h * 8 + 1], a2 = sA[h * 8 + 2],
                    a3 = sA[h * 8 + 3], a4 = sA[h * 8 + 4], a5 = sA[h * 8 + 5],
                    a6 = sA[h * 8 + 6];
        #pragma unroll
        for (int j = 0; j < 2; ++j)
            p[h][j] = fmaf(u0[j], a0, fmaf(u1[j], a1, fmaf(u2[j], a2,
                      fmaf(u3[j], a3, fmaf(u4[j], a4, fmaf(u5[j], a5, a6))))));
    }

    for (int c = 0; c < 64; ++c) {
        const float* wp = &sWp[c * 32];
        #pragma unroll
        for (int h = 0; h < 4; ++h) {
            const float4 wa = *(const float4*)&wp[h * 8];
            const float4 wb = *(const float4*)&wp[h * 8 + 4];
            #pragma unroll
            for (int j = 0; j < 2; ++j) {
                float t = fmaf(u0[j], wa.x,
                          fmaf(u1[j], wa.y,
                          fmaf(u2[j], wa.z,
                          fmaf(u3[j], wa.w,
                          fmaf(u4[j], wb.x,
                          fmaf(u5[j], wb.y, wb.z))))));
                p[h][j] = fmaf(fabsf(t), wb.w, p[h][j]);
            }
        }
    }

    #pragma unroll
    for (int h = 0; h < 4; ++h)
        *(float2*)&alpha1[(size_t)h * E_AUG + e0] = make_float2(p[h][0], p[h][1]);
}

// ---------------- Fused: l1 softmax + h build + bf16 MFMA projections ----------------

__global__ __launch_bounds__(256) void l1out_fused_kernel(
    const float* __restrict__ x, const int* __restrict__ offs,
    const int* __restrict__ e_src, const float* __restrict__ alpha1,
    const float4* __restrict__ wpk4, const ushort16* __restrict__ Wt,
    const float* __restrict__ b2l, const float* __restrict__ b2r,
    ushort16* __restrict__ xl2b, ushort16* __restrict__ xr2b) {
    __shared__ short hlds[64 * 256];    // 32 KB bf16 h tile
    __shared__ float4 swpk[256];        // 4 KB build coeffs
    const int tid = threadIdx.x;
    const int n0 = blockIdx.x * 64;
    const int lane = tid & 63, w = tid >> 6;

    swpk[tid] = wpk4[tid];

    // ---- phase 0: online softmax for (node, head) ----
    const int nl = tid >> 2, head = tid & 3;
    const int node = n0 + nl;
    float S1 = 0.0f, S2 = 0.0f;
    if (node < N_NODES) {
        const int beg = offs[node], end = offs[node + 1];
        const float* ap = alpha1 + (size_t)head * E_AUG;
        float amax = -1e30f, den = 0.0f, s1 = 0.0f, s2 = 0.0f;
        for (int e = beg; e < end; ++e) {
            float lg = ap[e];
            int s = e_src[e];
            float2 xs = *(const float2*)&x[2 * s];
            float m = fmaxf(amax, lg);
            float sc = __expf(amax - m);
            float wt = __expf(lg - m);
            den = fmaf(den, sc, wt);
            s1 = fmaf(s1, sc, wt * xs.x);
            s2 = fmaf(s2, sc, wt * xs.y);
            amax = m;
        }
        float inv = 1.0f / (den + 1e-16f);
        S1 = s1 * inv;
        S2 = s2 * inv;
    }
    __syncthreads();   // swpk ready

    // ---- phase 1: build h slice (head segment of 64 channels) ----
    {
        const int kseg = head * 64;
        const int swz = (nl & 7) << 3;
        for (int i = 0; i < 8; ++i) {
            short8v hv;
            #pragma unroll
            for (int j = 0; j < 8; ++j) {
                float4 wv = swpk[kseg + i * 8 + j];
                float g = fmaf(wv.x, S1, fmaf(wv.y, S2, wv.z));
                g = g > 0.0f ? g : (__expf(g) - 1.0f);
                hv[j] = (short)f2bf(g);
            }
            *(short8v*)&hlds[(nl * 256 + kseg + i * 8) ^ swz] = hv;
        }
    }

    // ---- B fragments ----
    short8v bfrag[2][8];
    {
        const int bc = w * 32 + (lane & 15);
        const int k0 = (lane >> 4) * 8;
        #pragma unroll
        for (int ct = 0; ct < 2; ++ct)
            #pragma unroll
            for (int kb = 0; kb < 8; ++kb)
                bfrag[ct][kb] = *(const short8v*)&Wt[(size_t)(bc + ct * 16) * 256 + kb * 32 + k0];
    }
    __syncthreads();

    // ---- phase 2: MFMA 4 row-tiles x 2 col-tiles x 8 k-blocks ----
    f32x4 acc[4][2];
    #pragma unroll
    for (int rt = 0; rt < 4; ++rt)
        #pragma unroll
        for (int ct = 0; ct < 2; ++ct)
            acc[rt][ct] = (f32x4){0.0f, 0.0f, 0.0f, 0.0f};

    const int arow = lane & 15, ak0 = (lane >> 4) * 8;
    #pragma unroll
    for (int rt = 0; rt < 4; ++rt) {
        const int n = rt * 16 + arow;
        const int swz = (n & 7) << 3;
        #pragma unroll
        for (int kb = 0; kb < 8; ++kb) {
            short8v a = *(const short8v*)&hlds[(n * 256 + kb * 32 + ak0) ^ swz];
            acc[rt][0] = __builtin_amdgcn_mfma_f32_16x16x32_bf16(a, bfrag[0][kb], acc[rt][0], 0, 0, 0);
            acc[rt][1] = __builtin_amdgcn_mfma_f32_16x16x32_bf16(a, bfrag[1][kb], acc[rt][1], 0, 0, 0);
        }
    }

    // ---- epilogue: bf16 store ----
    #pragma unroll
    for (int ct = 0; ct < 2; ++ct) {
        const int c = w * 32 + ct * 16 + (lane & 15);
        const bool isL = (c < 64);
        const int cc = isL ? c : c - 64;
        const float bias = isL ? b2l[cc] : b2r[cc];
        ushort16* dst = isL ? xl2b : xr2b;
        #pragma unroll
        for (int rt = 0; rt < 4; ++rt)
            #pragma unroll
            for (int r = 0; r < 4; ++r) {
                int nn = n0 + rt * 16 + (lane >> 4) * 4 + r;
                if (nn < N_NODES) dst[nn * 64 + cc] = f2bf(acc[rt][ct][r] + bias);
            }
    }
}

// ---------------- Layer 2 logits: 4 edges per wave, 16-lane dot ----------------

__global__ __launch_bounds__(256) void l2_logit_kernel(
    const ushort16* __restrict__ xl2b, const ushort16* __restrict__ xr2b,
    const int4* __restrict__ epk,
    const float* __restrict__ W2e, const float* __restrict__ att2,
    float* __restrict__ alpha2) {
    __shared__ float sWe[128], satt[64];
    const int tid = threadIdx.x;
    if (tid < 128) sWe[tid] = W2e[tid];
    if (tid < 64) satt[tid] = att2[tid];
    __syncthreads();

    const int lane = tid & 63, w = tid >> 6;
    const int e = blockIdx.x * 16 + w * 4 + (lane >> 4);   // E_AUG % 16 == 0

    const int4 v = epk[e];
    const int s = v.x, d = v.y;
    const float ae0 = __int_as_float(v.z), ae1 = __int_as_float(v.w);
    const int cl = lane & 15;

    float acc = 0.0f;
    #pragma unroll
    for (int q = 0; q < 4; ++q) {
        const int c = cl + q * 16;
        const float xl = bf2f(xl2b[s * 64 + c]);
        const float xr = bf2f(xr2b[d * 64 + c]);
        float t = xl + xr + fmaf(ae0, sWe[c], ae1 * sWe[64 + c]);
        t = t > 0.0f ? t : 0.2f * t;
        acc = fmaf(t, satt[c], acc);
    }
    #pragma unroll
    for (int off = 8; off; off >>= 1) acc += __shfl_xor(acc, off);
    if (cl == 0) alpha2[e] = acc;
}

// ---------------- Layer 2 aggregation: wave per node, no shuffles ----------------

__global__ __launch_bounds__(256) void l2_aggr_kernel(
    const ushort16* __restrict__ xl2b, const int* __restrict__ offs,
    const int* __restrict__ e_src, const float* __restrict__ alpha2,
    float* __restrict__ pblock) {
    __shared__ float sp[4][64];
    const int tid = threadIdx.x;
    const int l = tid & 63, w = tid >> 6;
    const int n = blockIdx.x * 4 + w;
    const int beg = offs[n], end = offs[n + 1];

    float amax = -1e30f, den = 0.0f, acc = 0.0f;
    int e = beg;
    for (; e + 4 <= end; e += 4) {
        const float4 a4 = *(const float4*)&alpha2[e];
        const int s0 = e_src[e], s1 = e_src[e + 1], s2 = e_src[e + 2], s3 = e_src[e + 3];
        const float xl0 = bf2f(xl2b[s0 * 64 + l]);
        const float xl1 = bf2f(xl2b[s1 * 64 + l]);
        const float xl2 = bf2f(xl2b[s2 * 64 + l]);
        const float xl3 = bf2f(xl2b[s3 * 64 + l]);
        const float mnew = fmaxf(fmaxf(amax, fmaxf(a4.x, a4.y)), fmaxf(a4.z, a4.w));
        const float sc = __expf(amax - mnew);
        const float w0 = __expf(a4.x - mnew), w1 = __expf(a4.y - mnew);
        const float w2 = __expf(a4.z - mnew), w3 = __expf(a4.w - mnew);
        den = fmaf(den, sc, (w0 + w1) + (w2 + w3));
        acc = fmaf(acc, sc, fmaf(w0, xl0, fmaf(w1, xl1, fmaf(w2, xl2, w3 * xl3))));
        amax = mnew;
    }
    for (; e < end; ++e) {
        const float a = alpha2[e];
        const int s = e_src[e];
        const float xl = bf2f(xl2b[s * 64 + l]);
        const float mnew = fmaxf(amax, a);
        const float sc = __expf(amax - mnew);
        const float ww = __expf(a - mnew);
        den = fmaf(den, sc, ww);
        acc = fmaf(acc, sc, ww * xl);
        amax = mnew;
    }
    sp[w][l] = acc / (den + 1e-16f);
    __syncthreads();
    if (tid < 64) {
        float v = sp[0][l] + sp[1][l] + sp[2][l] + sp[3][l];
        pblock[blockIdx.x * 64 + l] = v;
    }
}

// ---------------- final pool ----------------

__global__ __launch_bounds__(256) void pool_final_kernel(const float* __restrict__ pblock,
                                                         const float* __restrict__ bias2,
                                                         float* __restrict__ d_out) {
    __shared__ float s[256];
    int tid = threadIdx.x;
    int l = tid & 63, q = tid >> 6;
    float local = 0.0f;
    for (int r = blockIdx.x * 4 + q; r < 12500; r += 64 * 4)
        local += pblock[r * 64 + l];
    s[tid] = local;
    __syncthreads();
    if (tid < 64) {
        float v = s[tid] + s[tid + 64] + s[tid + 128] + s[tid + 192];
        atomicAdd(&d_out[tid], v * (1.0f / N_NODES));
        if (blockIdx.x == 0) atomicAdd(&d_out[tid], bias2[tid]);
    }
}

// ---------------- Host launch ----------------

extern "C" void kernel_launch(void* const* d_in, const int* in_sizes, int n_in,
                              void* d_out, int out_size, void* d_ws, size_t ws_size,
                              hipStream_t stream) {
    const float* x     = (const float*)d_in[0];
    const float* eattr = (const float*)d_in[1];
    const float* W1l   = (const float*)d_in[2];
    const float* b1l   = (const float*)d_in[3];
    const float* W1r   = (const float*)d_in[4];
    const float* b1r   = (const float*)d_in[5];
    const float* W1e   = (const float*)d_in[6];
    const float* att1  = (const float*)d_in[7];
    const float* bias1 = (const float*)d_in[8];
    const float* W2l   = (const float*)d_in[9];
    const float* b2l   = (const float*)d_in[10];
    const float* W2r   = (const float*)d_in[11];
    const float* b2r   = (const float*)d_in[12];
    const float* W2e   = (const float*)d_in[13];
    const float* att2  = (const float*)d_in[14];
    const float* bias2 = (const float*)d_in[15];
    const int*   ei    = (const int*)d_in[16];
    float* out = (float*)d_out;

    char* p = (char*)d_ws;
    auto alloc = [&](size_t bytes) -> void* {
        void* r = (void*)p;
        p += (bytes + 255) & ~(size_t)255;
        return r;
    };
    int*   deg    = (int*)alloc(N_NODES * 4);
    int*   cnt    = (int*)alloc(N_NODES * 4);
    int*   bcnt   = (int*)alloc(256 * 4);
    size_t zlen   = (size_t)((char*)bcnt - (char*)deg) + 256;
    int*   offs   = (int*)alloc((N_NODES + 1) * 4);
    int*   bsum   = (int*)alloc(256 * 4);
    int4*  stage  = (int4*)alloc((size_t)NBUCK * BCAP * 16);
    int4*  epk    = (int4*)alloc((size_t)E_AUG * 16);
    int*   e_src  = (int*)alloc(E_AUG * 4);
    float* alpha1 = (float*)alloc((size_t)E_AUG * 4 * 4);
    float* alpha2 = (float*)alloc((size_t)E_AUG * 4);
    float* Wpack  = (float*)alloc(256 * 8 * 4);
    float* Apack  = (float*)alloc(32 * 4);
    float4* wpk4  = (float4*)alloc(256 * 16);
    ushort16* Wt  = (ushort16*)alloc(128 * 256 * 2);
    ushort16* xl2b = (ushort16*)alloc((size_t)N_NODES * C2 * 2);
    ushort16* xr2b = (ushort16*)alloc((size_t)N_NODES * C2 * 2);
    float* pblock = (float*)alloc((size_t)12500 * 64 * 4);

    hipMemsetAsync(deg, 0, zlen, stream);
    hipMemsetAsync(d_out, 0, 64 * 4, stream);

    pass1_kernel<<<PACK_BLOCKS + HIST_BLOCKS, 256, 0, stream>>>(
        ei, eattr, W1l, b1l, W1r, b1r, W1e, att1, bias1, W2l, W2r,
        Wpack, Apack, wpk4, Wt, stage, bcnt);

    degk_kernel<<<NBUCK, 256, 0, stream>>>(stage, bcnt, deg);

    int nb = (N_NODES + 255) / 256;   // 196
    scan1_kernel<<<nb, 256, 0, stream>>>(deg, offs, bsum);
    scan23_kernel<<<nb, 256, 0, stream>>>(offs, bsum, nb);

    pass2_kernel<<<NBUCK * 4, 256, 0, stream>>>(stage, bcnt, offs, cnt, epk, e_src);
    loop_fill_kernel<<<nb, 256, 0, stream>>>(offs, epk, e_src);

    l1_alpha_kernel<<<(E_AUG / 2 + 255) / 256, 256, 0, stream>>>(x, epk, Wpack, Apack,
                                                                 alpha1);

    l1out_fused_kernel<<<(N_NODES + 63) / 64, 256, 0, stream>>>(x, offs, e_src, alpha1,
                                                                wpk4, Wt, b2l, b2r,
                                                                xl2b, xr2b);

    l2_logit_kernel<<<E_AUG / 16, 256, 0, stream>>>(xl2b, xr2b, epk, W2e, att2, alpha2);

    l2_aggr_kernel<<<N_NODES / 4, 256, 0, stream>>>(xl2b, offs, e_src, alpha2, pblock);

    pool_final_kernel<<<64, 256, 0, stream>>>(pblock, bias2, out);
}